// Round 1
// baseline (1163.800 us; speedup 1.0000x reference)
//
#include <hip/hip_runtime.h>
#include <math.h>

#define T_DIM 8192
#define H_DIM 4096
#define I_DIM 11008

typedef int v4i  __attribute__((ext_vector_type(4)));
typedef int v16i __attribute__((ext_vector_type(16)));

#define AS1(p) ((const __attribute__((address_space(1))) void*)(p))
#define AS3(p) ((__attribute__((address_space(3))) void*)(p))

// vmcnt(N) + barrier (tile-boundary certification point)
#define WAIT_VM_BAR(N) asm volatile("s_waitcnt vmcnt(" #N ")\n\ts_barrier" ::: "memory")
#define LGKM0 do { asm volatile("s_waitcnt lgkmcnt(0)" ::: "memory"); \
                   __builtin_amdgcn_sched_barrier(0); } while (0)

__device__ __forceinline__ v4i DSR(const char* p) {
  v4i r;
  unsigned a = (unsigned)(size_t)(const __attribute__((address_space(3))) char*)p;
  asm volatile("ds_read_b128 %0, %1" : "=v"(r) : "v"(a));
  return r;
}

__global__ void pack_i8(const int* __restrict__ src, char* __restrict__ dst, long n16) {
  long i = (long)blockIdx.x * blockDim.x + threadIdx.x;
  long stride = (long)gridDim.x * blockDim.x;
  for (; i < n16; i += stride) {
    const int4* s = (const int4*)src + i * 4;
    int4 a = s[0], b = s[1], c = s[2], d = s[3];
    int w0 = (a.x & 255) | ((a.y & 255) << 8) | ((a.z & 255) << 16) | (a.w << 24);
    int w1 = (b.x & 255) | ((b.y & 255) << 8) | ((b.z & 255) << 16) | (b.w << 24);
    int w2 = (c.x & 255) | ((c.y & 255) << 8) | ((c.z & 255) << 16) | (c.w << 24);
    int w3 = (d.x & 255) | ((d.y & 255) << 8) | ((d.z & 255) << 16) | (d.w << 24);
    ((int4*)dst)[i] = make_int4(w0, w1, w2, w3);
  }
}

#define STG(buf, src, k0, coff) \
  __builtin_amdgcn_global_load_lds(AS1((src) + (k0)), AS3((buf) + (coff) + dd), 16, 0, 0)

// ---------------- gate+up fused GEMM: 256x128 tile, BK=128, 8 waves, 2x64KB dbuf.
// 32x32x32 i8 MFMA; 4 free-running phases per K-tile (one ds_read->lgkm0->MFMA
// cluster per 32-wide k-step); ONE vmcnt(0)+barrier per tile at the boundary.
// LDS: A0..A3 @0/8/16/24K (64 rows each) | Bg @32K (128 rows) | Bu @48K (128 rows),
// 128B rows with 16B-slot XOR swizzle: slot_sw = slot ^ (row&7).
__global__ __launch_bounds__(512, 2) void gemm_gateup(
    const char* __restrict__ A, const char* __restrict__ Bg, const char* __restrict__ Bu,
    const float* __restrict__ ga_p, const float* __restrict__ gb,
    const float* __restrict__ ua_p, const float* __restrict__ ub,
    char* __restrict__ Q)
{
  __shared__ char lds[2][65536];
  const int tid = threadIdx.x;
  const int l = tid & 63;
  const int w = tid >> 6;
  const int wm = w >> 2, wn = w & 3;

  // XCD-chunked bijection (nwg=2752, %8==0) + 4x2 supertile.
  const int q8 = 2752 / 8;
  int bid = blockIdx.x;
  int wgid = (bid & 7) * q8 + (bid >> 3);
  int st = wgid >> 3, r = wgid & 7;
  int sm = st / 43, sn = st - sm * 43;
  const int m0 = (sm * 4 + (r & 3)) * 256;
  const int n0 = (sn * 2 + (r >> 2)) * 128;

  v16i accg[4], accu[4];
#pragma unroll
  for (int i = 0; i < 4; ++i) {
#pragma unroll
    for (int j = 0; j < 16; ++j) { accg[i][j] = 0; accu[i][j] = 0; }
  }

  // Staging: thread fills 16B at chunk_off + tid*16 (linear LDS dest);
  // global source col pre-swizzled so read-side swizzle is consistent.
  const int r8 = tid >> 3;
  const int gc = ((tid & 7) << 4) ^ ((r8 & 7) << 4);
  const char* pA0 = A  + (size_t)(m0 +       r8) * H_DIM + gc;
  const char* pA1 = A  + (size_t)(m0 +  64 + r8) * H_DIM + gc;
  const char* pA2 = A  + (size_t)(m0 + 128 + r8) * H_DIM + gc;
  const char* pA3 = A  + (size_t)(m0 + 192 + r8) * H_DIM + gc;
  const char* pG0 = Bg + (size_t)(n0 +       r8) * H_DIM + gc;
  const char* pG1 = Bg + (size_t)(n0 +  64 + r8) * H_DIM + gc;
  const char* pU0 = Bu + (size_t)(n0 +       r8) * H_DIM + gc;
  const char* pU1 = Bu + (size_t)(n0 +  64 + r8) * H_DIM + gc;
  const int dd = tid * 16;

  // 32x32x32 fragment offsets: A row = wm*128+mi*32+(l&31), k-group = l>>5,
  // byte slot (ks*2 + kg2) ^ (row&7). Per 16-lane group: 8 slots x 2 lanes.
  const int li32 = l & 31, kg2 = l >> 5;
  int oA[4][4], oB[4];
#pragma unroll
  for (int ks = 0; ks < 4; ++ks) {
    int slot = (((ks * 2 + kg2) ^ (li32 & 7)) << 4);
#pragma unroll
    for (int mi = 0; mi < 4; ++mi) oA[ks][mi] = (wm * 128 + mi * 32 + li32) * 128 + slot;
    oB[ks] = (wn * 32 + li32) * 128 + slot;
  }

  const int nk = H_DIM / 128;  // 32

  {  // Prologue: stage tile 0 fully, certify everything once.
    char* B0 = lds[0];
    STG(B0, pA0, 0, 0);     STG(B0, pA1, 0, 8192);  STG(B0, pA2, 0, 16384); STG(B0, pA3, 0, 24576);
    STG(B0, pG0, 0, 32768); STG(B0, pG1, 0, 40960); STG(B0, pU0, 0, 49152); STG(B0, pU1, 0, 57344);
    WAIT_VM_BAR(0);
  }

#define GUPH(ks, ...)                                                                    \
  do {                                                                                   \
    v4i gf = DSR(L + 32768 + oB[ks]);                                                    \
    v4i uf = DSR(L + 49152 + oB[ks]);                                                    \
    v4i a0 = DSR(L + oA[ks][0]);                                                         \
    v4i a1 = DSR(L + oA[ks][1]);                                                         \
    v4i a2 = DSR(L + oA[ks][2]);                                                         \
    v4i a3 = DSR(L + oA[ks][3]);                                                         \
    __VA_ARGS__                                                                          \
    LGKM0;                                                                               \
    __builtin_amdgcn_s_setprio(1);                                                       \
    accg[0] = __builtin_amdgcn_mfma_i32_32x32x32_i8(a0, gf, accg[0], 0, 0, 0);           \
    accu[0] = __builtin_amdgcn_mfma_i32_32x32x32_i8(a0, uf, accu[0], 0, 0, 0);           \
    accg[1] = __builtin_amdgcn_mfma_i32_32x32x32_i8(a1, gf, accg[1], 0, 0, 0);           \
    accu[1] = __builtin_amdgcn_mfma_i32_32x32x32_i8(a1, uf, accu[1], 0, 0, 0);           \
    accg[2] = __builtin_amdgcn_mfma_i32_32x32x32_i8(a2, gf, accg[2], 0, 0, 0);           \
    accu[2] = __builtin_amdgcn_mfma_i32_32x32x32_i8(a2, uf, accu[2], 0, 0, 0);           \
    accg[3] = __builtin_amdgcn_mfma_i32_32x32x32_i8(a3, gf, accg[3], 0, 0, 0);           \
    accu[3] = __builtin_amdgcn_mfma_i32_32x32x32_i8(a3, uf, accu[3], 0, 0, 0);           \
    __builtin_amdgcn_s_setprio(0);                                                       \
  } while (0)

  for (int t = 0; t < nk; ++t) {
    const char* L = lds[t & 1];
    char* SB = lds[(t & 1) ^ 1];
    const bool son = (t + 1) < nk;
    const int sk = (t + 1) * 128;

    GUPH(0, if (son) { STG(SB, pA0, sk, 0);     STG(SB, pA1, sk, 8192);
                       STG(SB, pA2, sk, 16384); STG(SB, pA3, sk, 24576); });
    GUPH(1, if (son) { STG(SB, pG0, sk, 32768); STG(SB, pG1, sk, 40960);
                       STG(SB, pU0, sk, 49152); STG(SB, pU1, sk, 57344); });
    GUPH(2, );
    GUPH(3, );
    // Tile boundary: per-wave vmcnt(0) retires its 8 staging loads (issued
    // >=2 phases ago -> HBM latency covered); barrier certifies SB for all
    // waves AND guarantees everyone's ds_reads of L are done before next
    // tile's STG overwrites it. Single sync point per K-tile.
    WAIT_VM_BAR(0);
  }
#undef GUPH

  // Epilogue: dequant -> SiLU(g)*u -> round-half-even -> clamp -> int8.
  // 32x32 C/D: col = l&31, row = (reg&3) + 8*(reg>>2) + 4*(l>>5).
  const float ga = *ga_p, ua = *ua_p;
  const int col = n0 + wn * 32 + li32;
  const float gbv = gb[col], ubv = ub[col];
#pragma unroll
  for (int mi = 0; mi < 4; ++mi) {
    const int rowb = m0 + wm * 128 + mi * 32 + kg2 * 4;
#pragma unroll
    for (int rq = 0; rq < 4; ++rq) {
#pragma unroll
      for (int rr = 0; rr < 4; ++rr) {
        const int rg = rq * 4 + rr;
        float g = (float)accg[mi][rg] * ga + gbv;
        float u = (float)accu[mi][rg] * ua + ubv;
        float x1 = g / (1.0f + expf(-g));
        float x = rintf(x1 * u);
        x = fminf(fmaxf(x, -128.0f), 127.0f);
        Q[(size_t)(rowb + rq * 8 + rr) * I_DIM + col] = (char)(int)x;
      }
    }
  }
}

// ---------------- down GEMM: 256x256 tile, BK=128, 8 waves, 2x64KB dbuf.
// Same 32x32x32 free-running phase structure. LDS: A0..A3 @0..24K | B0..B3 @32..56K.
__global__ __launch_bounds__(512, 2) void gemm_down(
    const char* __restrict__ Qm, const char* __restrict__ Bd,
    const float* __restrict__ da_p, const float* __restrict__ db,
    float* __restrict__ out)
{
  __shared__ char lds[2][65536];
  const int tid = threadIdx.x;
  const int l = tid & 63;
  const int w = tid >> 6;
  const int wm = w >> 2, wn = w & 3;

  const int q8 = 512 / 8;
  int bid = blockIdx.x;
  int wgid = (bid & 7) * q8 + (bid >> 3);
  int st = wgid >> 3, r = wgid & 7;
  int sm = st >> 3, sn = st & 7;
  const int m0 = (sm * 4 + (r & 3)) * 256;
  const int n0 = (sn * 2 + (r >> 2)) * 256;

  v16i acc[4][2];
#pragma unroll
  for (int i = 0; i < 4; ++i) {
#pragma unroll
    for (int n = 0; n < 2; ++n) {
#pragma unroll
      for (int j = 0; j < 16; ++j) acc[i][n][j] = 0;
    }
  }

  const int r8 = tid >> 3;
  const int gc = ((tid & 7) << 4) ^ ((r8 & 7) << 4);
  const char* pA0 = Qm + (size_t)(m0 +       r8) * I_DIM + gc;
  const char* pA1 = Qm + (size_t)(m0 +  64 + r8) * I_DIM + gc;
  const char* pA2 = Qm + (size_t)(m0 + 128 + r8) * I_DIM + gc;
  const char* pA3 = Qm + (size_t)(m0 + 192 + r8) * I_DIM + gc;
  const char* pB0 = Bd + (size_t)(n0 +       r8) * I_DIM + gc;
  const char* pB1 = Bd + (size_t)(n0 +  64 + r8) * I_DIM + gc;
  const char* pB2 = Bd + (size_t)(n0 + 128 + r8) * I_DIM + gc;
  const char* pB3 = Bd + (size_t)(n0 + 192 + r8) * I_DIM + gc;
  const int dd = tid * 16;

  const int li32 = l & 31, kg2 = l >> 5;
  int oA[4][4], oB[4][2];
#pragma unroll
  for (int ks = 0; ks < 4; ++ks) {
    int slot = (((ks * 2 + kg2) ^ (li32 & 7)) << 4);
#pragma unroll
    for (int mi = 0; mi < 4; ++mi) oA[ks][mi] = (wm * 128 + mi * 32 + li32) * 128 + slot;
#pragma unroll
    for (int ni = 0; ni < 2; ++ni) oB[ks][ni] = (wn * 64 + ni * 32 + li32) * 128 + slot;
  }

  const int nk = I_DIM / 128;  // 86

  {
    char* B0 = lds[0];
    STG(B0, pA0, 0, 0);     STG(B0, pA1, 0, 8192);  STG(B0, pA2, 0, 16384); STG(B0, pA3, 0, 24576);
    STG(B0, pB0, 0, 32768); STG(B0, pB1, 0, 40960); STG(B0, pB2, 0, 49152); STG(B0, pB3, 0, 57344);
    WAIT_VM_BAR(0);
  }

#define DNPH(ks, ...)                                                                    \
  do {                                                                                   \
    v4i bf0 = DSR(L + 32768 + oB[ks][0]);                                                \
    v4i bf1 = DSR(L + 32768 + oB[ks][1]);                                                \
    v4i a0 = DSR(L + oA[ks][0]);                                                         \
    v4i a1 = DSR(L + oA[ks][1]);                                                         \
    v4i a2 = DSR(L + oA[ks][2]);                                                         \
    v4i a3 = DSR(L + oA[ks][3]);                                                         \
    __VA_ARGS__                                                                          \
    LGKM0;                                                                               \
    __builtin_amdgcn_s_setprio(1);                                                       \
    acc[0][0] = __builtin_amdgcn_mfma_i32_32x32x32_i8(a0, bf0, acc[0][0], 0, 0, 0);      \
    acc[0][1] = __builtin_amdgcn_mfma_i32_32x32x32_i8(a0, bf1, acc[0][1], 0, 0, 0);      \
    acc[1][0] = __builtin_amdgcn_mfma_i32_32x32x32_i8(a1, bf0, acc[1][0], 0, 0, 0);      \
    acc[1][1] = __builtin_amdgcn_mfma_i32_32x32x32_i8(a1, bf1, acc[1][1], 0, 0, 0);      \
    acc[2][0] = __builtin_amdgcn_mfma_i32_32x32x32_i8(a2, bf0, acc[2][0], 0, 0, 0);      \
    acc[2][1] = __builtin_amdgcn_mfma_i32_32x32x32_i8(a2, bf1, acc[2][1], 0, 0, 0);      \
    acc[3][0] = __builtin_amdgcn_mfma_i32_32x32x32_i8(a3, bf0, acc[3][0], 0, 0, 0);      \
    acc[3][1] = __builtin_amdgcn_mfma_i32_32x32x32_i8(a3, bf1, acc[3][1], 0, 0, 0);      \
    __builtin_amdgcn_s_setprio(0);                                                       \
  } while (0)

  for (int t = 0; t < nk; ++t) {
    const char* L = lds[t & 1];
    char* SB = lds[(t & 1) ^ 1];
    const bool son = (t + 1) < nk;
    const int sk = (t + 1) * 128;

    DNPH(0, if (son) { STG(SB, pA0, sk, 0);     STG(SB, pA1, sk, 8192);
                       STG(SB, pA2, sk, 16384); STG(SB, pA3, sk, 24576); });
    DNPH(1, if (son) { STG(SB, pB0, sk, 32768); STG(SB, pB1, sk, 40960);
                       STG(SB, pB2, sk, 49152); STG(SB, pB3, sk, 57344); });
    DNPH(2, );
    DNPH(3, );
    WAIT_VM_BAR(0);
  }
#undef DNPH

  const float da = *da_p;
#pragma unroll
  for (int ni = 0; ni < 2; ++ni) {
    const int col = n0 + wn * 64 + ni * 32 + li32;
    const float dbv = db[col];
#pragma unroll
    for (int mi = 0; mi < 4; ++mi) {
      const int rowb = m0 + wm * 128 + mi * 32 + kg2 * 4;
#pragma unroll
      for (int rq = 0; rq < 4; ++rq) {
#pragma unroll
        for (int rr = 0; rr < 4; ++rr)
          out[(size_t)(rowb + rq * 8 + rr) * H_DIM + col] =
              (float)acc[mi][ni][rq * 4 + rr] * da + dbv;
      }
    }
  }
}

extern "C" void kernel_launch(void* const* d_in, const int* in_sizes, int n_in,
                              void* d_out, int out_size, void* d_ws, size_t ws_size,
                              hipStream_t stream) {
  const int*   hs = (const int*)d_in[0];
  const int*   gw = (const int*)d_in[1];
  const float* ga = (const float*)d_in[2];
  const float* gb = (const float*)d_in[3];
  const int*   uw = (const int*)d_in[4];
  const float* ua = (const float*)d_in[5];
  const float* ub = (const float*)d_in[6];
  const int*   dw = (const int*)d_in[7];
  const float* da = (const float*)d_in[8];
  const float* db = (const float*)d_in[9];

  char* ws   = (char*)d_ws;
  char* hid8 = ws;
  char* g8   = hid8 + (size_t)T_DIM * H_DIM;
  char* u8   = g8   + (size_t)I_DIM * H_DIM;
  char* d8   = u8   + (size_t)I_DIM * H_DIM;
  char* q8   = d8   + (size_t)I_DIM * H_DIM;

  pack_i8<<<2048, 256, 0, stream>>>(hs, hid8, (long)T_DIM * H_DIM / 16);
  pack_i8<<<2048, 256, 0, stream>>>(gw, g8,   (long)I_DIM * H_DIM / 16);
  pack_i8<<<2048, 256, 0, stream>>>(uw, u8,   (long)I_DIM * H_DIM / 16);
  pack_i8<<<2048, 256, 0, stream>>>(dw, d8,   (long)I_DIM * H_DIM / 16);

  gemm_gateup<<<2752, 512, 0, stream>>>(hid8, g8, u8, ga, gb, ua, ub, q8);
  gemm_down<<<512, 512, 0, stream>>>(q8, d8, da, db, (float*)d_out);
}